// Round 10
// baseline (192.226 us; speedup 1.0000x reference)
//
#include <hip/hip_runtime.h>

#define SQ 2048
#define DH 64
#define NH 12
#define NBH 48          // B*H
#define QTILE 64        // q rows per block: 2 subtiles x 2 kk-half waves
#define KTILE 64        // keys per block-iteration (32 per wave)
#define NITER (SQ / KTILE)
#define NQT (SQ / QTILE)   // 32 -> 1536 blocks = 6 blocks/CU

typedef short short8 __attribute__((ext_vector_type(8)));
typedef float f32x4  __attribute__((ext_vector_type(4)));
typedef float f32x16 __attribute__((ext_vector_type(16)));
typedef int   i32x4 __attribute__((ext_vector_type(4)));

#define MFMA32(a, b, c) __builtin_amdgcn_mfma_f32_32x32x16_bf16(a, b, c, 0, 0, 0)

typedef __attribute__((address_space(1))) const void* gas_ptr;
typedef __attribute__((address_space(3))) void* las_ptr;

__device__ __forceinline__ void load_lds16(const void* g, void* l) {
    __builtin_amdgcn_global_load_lds((gas_ptr)g, (las_ptr)l, 16, 0, 0);
}

// two fp32 -> packed bf16x2 (low = a, high = b), RTNE
#if defined(__has_builtin) && __has_builtin(__builtin_amdgcn_cvt_pk_bf16_f32)
typedef __bf16 bf16x2_t __attribute__((ext_vector_type(2)));
__device__ __forceinline__ unsigned pk2bf(float a, float b) {
    bf16x2_t v = __builtin_amdgcn_cvt_pk_bf16_f32(a, b);
    union { bf16x2_t v; unsigned u; } c; c.v = v; return c.u;
}
#else
__device__ __forceinline__ unsigned pk2bf(float a, float b) {
    union { float f; unsigned u; } x, y; x.f = a; y.f = b;
    unsigned ra = x.u + 0x7FFFu + ((x.u >> 16) & 1u);
    unsigned rb = y.u + 0x7FFFu + ((y.u >> 16) & 1u);
    return (ra >> 16) | (rb & 0xFFFF0000u);
}
#endif

// ------- fused pre-pass: K fp32->bf16 (blocks 0..3071)  |  V transpose (rest) -------
#define KCONV_BLOCKS (NBH * SQ * DH / 8 / 256)   // 3072
__global__ __launch_bounds__(256)
void prepass(const float* __restrict__ K, short* __restrict__ Kb,
             const float* __restrict__ V, short* __restrict__ Vt) {
    __shared__ float Ls[64][68];
    if (blockIdx.x < KCONV_BLOCKS) {
        const size_t i = (size_t)(blockIdx.x * 256 + threadIdx.x) * 8;
        f32x4 a = *(const f32x4*)&K[i];
        f32x4 b = *(const f32x4*)&K[i + 4];
        unsigned o[4] = { pk2bf(a[0], a[1]), pk2bf(a[2], a[3]),
                          pk2bf(b[0], b[1]), pk2bf(b[2], b[3]) };
        *(i32x4*)&Kb[i] = *(i32x4*)o;
        return;
    }
    const int bx = blockIdx.x - KCONV_BLOCKS;
    const int st = bx & 31;
    const int bh = bx >> 5;
    const int b = bh / NH, h = bh % NH;
    const int s0 = st * 64;
    const float* src = V + ((size_t)b * SQ * NH + (size_t)h) * DH;
    const int dg = threadIdx.x & 15;
    const int sl = threadIdx.x >> 4;
    #pragma unroll
    for (int p = 0; p < 4; ++p) {
        const int row = p * 16 + sl;
        *(f32x4*)&Ls[row][dg * 4] =
            *(const f32x4*)&src[(size_t)(s0 + row) * (NH * DH) + dg * 4];
    }
    __syncthreads();
    const int dr = threadIdx.x >> 2;
    const int sc = (threadIdx.x & 3) * 16;
    unsigned out[8];
    #pragma unroll
    for (int jj = 0; jj < 8; ++jj)
        out[jj] = pk2bf(Ls[sc + 2 * jj][dr], Ls[sc + 2 * jj + 1][dr]);
    short* dst = Vt + (size_t)bh * DH * SQ + (size_t)dr * SQ + s0 + sc;
    *(i32x4*)(dst)     = *(i32x4*)&out[0];
    *(i32x4*)(dst + 8) = *(i32x4*)&out[4];
}

// ------- main fused attention: 32x32x16 MFMA, kk-split wave pairs -------
// Block: 4 waves. Wave w: q-subtile pr=w>>1 (32 rows), kk-half h=w&1 (32 keys
// of each 64-key tile). Single-buffer LDS: K tile @0 (8KB, [kk][d]),
// V^T tile @8192 (8KB, [d][kk]). XOR chunk swizzle (chunk c of row r at
// c^(r&7)). O/lp partials merged across the wave pair once at the end.
__global__ __launch_bounds__(256, 6)
void attn_fused_kernel(const float* __restrict__ Q,
                       const short* __restrict__ Kb,   // bf16 [BH][S][D]
                       const short* __restrict__ Vtg,  // bf16 [BH][D][S]
                       float* __restrict__ O) {
    __shared__ __align__(16) char L[16384];
    __shared__ float lpb[2][64];

    const int tid  = threadIdx.x;
    const int lane = tid & 63;
    const int w    = tid >> 6;
    const int m31  = lane & 31;
    const int hl   = lane >> 5;
    const int l7   = m31 & 7;
    const int h    = w & 1;       // kk-half
    const int pr   = w >> 1;      // q-subtile

    const int bx = blockIdx.x;
    const int qt = bx & (NQT - 1);
    const int bh = bx >> 5;
    const int q0 = qt * QTILE + 32 * pr;   // this wave's q base

    const float* Qb  = Q   + (size_t)bh * SQ * DH;
    const short* Kbh = Kb  + (size_t)bh * SQ * DH;
    const short* Vbh = Vtg + (size_t)bh * DH * SQ;
    float*       Ob  = O   + (size_t)bh * SQ * DH;

    // scale folded into Q, exp as exp2: 1/sqrt(768) * log2(e)
    const float qscale = 0.03608439182435161f * 1.4426950408889634f;

    // ---- Q fragments (B operand: n=m31 -> q row, k=d=16*s+8*hl+j) ----
    short8 qf[4];
    {
        const int qrow = q0 + m31;
        #pragma unroll
        for (int s = 0; s < 4; ++s) {
            const float* src = Qb + (size_t)qrow * DH + 16 * s + 8 * hl;
            f32x4 qa = *(const f32x4*)src;
            f32x4 qb = *(const f32x4*)(src + 4);
            union { unsigned u[4]; short8 v; } f;
            f.u[0] = pk2bf(qa[0] * qscale, qa[1] * qscale);
            f.u[1] = pk2bf(qa[2] * qscale, qa[3] * qscale);
            f.u[2] = pk2bf(qb[0] * qscale, qb[1] * qscale);
            f.u[3] = pk2bf(qb[2] * qscale, qb[3] * qscale);
            qf[s] = f.v;
        }
    }

    // ---- staging source pointers (lane-constant swizzle), block-cooperative ----
    const int gk = (lane & 7) ^ (lane >> 3);
    const int rr = w * 8 + (lane >> 3);
    const short* kg0 = Kbh + (size_t)rr * DH + gk * 8;
    const short* kg1 = kg0 + 32 * DH;
    const short* vg0 = Vbh + (size_t)rr * SQ + gk * 8;
    const short* vg1 = vg0 + 32 * SQ;
    const int wslot = w * 1024;

    // ---- loop-invariant LDS frag byte offsets ----
    // K A-frag: row 32h+m31, d-chunk (2s+hl), swizzled
    int kaoff[4];
    #pragma unroll
    for (int s = 0; s < 4; ++s)
        kaoff[s] = (32 * h + m31) * 128 + (((2 * s + hl) ^ l7) * 16);
    // V B-frag: row d=m31 (+32 via +4096), kk-chunk (2s+hl+4h), swizzled
    int voff[2];
    #pragma unroll
    for (int s = 0; s < 2; ++s)
        voff[s] = m31 * 128 + (((2 * s + hl + 4 * h) ^ l7) * 16);

    f32x16 o0 = {}, o1 = {};
    float lp = 0.f;

    for (int it = 0; it < NITER; ++it) {
        __syncthreads();   // all waves done reading previous tile
        load_lds16(kg0, L + wslot);
        load_lds16(kg1, L + 4096 + wslot);
        load_lds16(vg0, L + 8192 + wslot);
        load_lds16(vg1, L + 12288 + wslot);
        kg0 += KTILE * DH; kg1 += KTILE * DH;
        vg0 += KTILE;      vg1 += KTILE;
        __syncthreads();   // vmcnt drained -> tiles visible

        // ---- S^T = K Q^T (4 MFMA): C col=q=m31, row=kkL=(reg&3)+8(reg>>2)+4hl ----
        f32x16 s0 = {};
        #pragma unroll
        for (int s = 0; s < 4; ++s) {
            short8 ka = *(const short8*)(L + kaoff[s]);
            s0 = MFMA32(ka, qf[s], s0);
        }

        // ---- exp + in-register C->A relayout (hl pair swap) ----
        short8 pfrag[2];
        #pragma unroll
        for (int wd = 0; wd < 2; ++wd) {
            float p[8];
            #pragma unroll
            for (int j = 0; j < 8; ++j)
                p[j] = __builtin_amdgcn_exp2f(s0[8 * wd + j]);
            lp += ((p[0] + p[1]) + (p[2] + p[3])) +
                  ((p[4] + p[5]) + (p[6] + p[7]));
            unsigned a0 = pk2bf(p[0], p[1]);
            unsigned a1 = pk2bf(p[2], p[3]);
            unsigned b0 = pk2bf(p[4], p[5]);
            unsigned b1 = pk2bf(p[6], p[7]);
            unsigned r0 = (unsigned)__shfl_xor((int)(hl ? a0 : b0), 32, 64);
            unsigned r1 = (unsigned)__shfl_xor((int)(hl ? a1 : b1), 32, 64);
            union { unsigned u[4]; short8 v; } fr;
            fr.u[0] = hl ? r0 : a0;
            fr.u[1] = hl ? r1 : a1;
            fr.u[2] = hl ? b0 : r0;
            fr.u[3] = hl ? b1 : r1;
            pfrag[wd] = fr.v;
        }

        // ---- O += P V (4 MFMA): A=P regs (m=q), B=V^T from LDS ----
        #pragma unroll
        for (int s = 0; s < 2; ++s) {
            short8 vb0 = *(const short8*)(L + 8192 + voff[s]);
            short8 vb1 = *(const short8*)(L + 12288 + voff[s]);
            o0 = MFMA32(pfrag[s], vb0, o0);
            o1 = MFMA32(pfrag[s], vb1, o1);
        }
    }

    // ---- merge wave-pair partials (different kk-halves, same q rows) ----
    float vsum = lp + __shfl_xor(lp, 32, 64);   // full kk-half sum for q=m31
    __syncthreads();                            // LDS tiles dead, reuse as merge buf
    float* mb = (float*)L;                      // pair pr region: 2048 floats
    if (h) {
        #pragma unroll
        for (int i = 0; i < 16; ++i) {
            mb[pr * 2048 + i * 64 + lane]        = o0[i];
            mb[pr * 2048 + 1024 + i * 64 + lane] = o1[i];
        }
        lpb[pr][lane] = vsum;
    }
    __syncthreads();
    if (!h) {
        const float vtot = vsum + lpb[pr][lane];
        const float linv = 1.0f / vtot;
        #pragma unroll
        for (int i = 0; i < 16; ++i) {
            o0[i] += mb[pr * 2048 + i * 64 + lane];
            o1[i] += mb[pr * 2048 + 1024 + i * 64 + lane];
        }
        #pragma unroll
        for (int reg = 0; reg < 16; ++reg) {
            const int qp = (reg & 3) + 8 * (reg >> 2) + 4 * hl;
            const float rl = __shfl(linv, qp, 64);
            const int q = q0 + qp;
            Ob[(size_t)q * DH + m31]      = o0[reg] * rl;
            Ob[(size_t)q * DH + 32 + m31] = o1[reg] * rl;
        }
    }
}

extern "C" void kernel_launch(void* const* d_in, const int* in_sizes, int n_in,
                              void* d_out, int out_size, void* d_ws, size_t ws_size,
                              hipStream_t stream) {
    const float* Q = (const float*)d_in[0];
    const float* K = (const float*)d_in[1];
    const float* V = (const float*)d_in[2];
    float* O = (float*)d_out;

    // workspace: bf16 K (12.6 MB) + bf16 V^T (12.6 MB)
    short* Kb  = (short*)d_ws;
    short* Vtg = Kb + (size_t)NBH * SQ * DH;

    prepass<<<dim3(KCONV_BLOCKS + NBH * 32), dim3(256), 0, stream>>>(K, Kb, V, Vtg);
    // 48 heads x 32 q-tiles = 1536 blocks = 6 blocks/CU; 16.5 KB LDS
    attn_fused_kernel<<<dim3(NBH * NQT), dim3(256), 0, stream>>>(Q, Kb, Vtg, O);
}

// Round 11
// 174.904 us; speedup vs baseline: 1.0990x; 1.0990x over previous
//
#include <hip/hip_runtime.h>

#define SQ 2048
#define DH 64
#define NH 12
#define NBH 48          // B*H
#define QTILE 128       // q rows per block (32 per wave)
#define KTILE 64        // keys per iteration
#define NITER (SQ / KTILE)
#define NQT (SQ / QTILE)   // 16 q-tiles -> 768 blocks = 3 blocks/CU

typedef short short8 __attribute__((ext_vector_type(8)));
typedef float f32x4  __attribute__((ext_vector_type(4)));
typedef float f32x16 __attribute__((ext_vector_type(16)));
typedef int   i32x4 __attribute__((ext_vector_type(4)));

#define MFMA32(a, b, c) __builtin_amdgcn_mfma_f32_32x32x16_bf16(a, b, c, 0, 0, 0)

typedef __attribute__((address_space(1))) const void* gas_ptr;
typedef __attribute__((address_space(3))) void* las_ptr;

__device__ __forceinline__ void load_lds16(const void* g, void* l) {
    // 16B/lane direct global->LDS DMA; LDS dest = wave-uniform base + lane*16
    __builtin_amdgcn_global_load_lds((gas_ptr)g, (las_ptr)l, 16, 0, 0);
}

// two fp32 -> packed bf16x2 (low = a, high = b), RTNE
#if defined(__has_builtin) && __has_builtin(__builtin_amdgcn_cvt_pk_bf16_f32)
typedef __bf16 bf16x2_t __attribute__((ext_vector_type(2)));
__device__ __forceinline__ unsigned pk2bf(float a, float b) {
    bf16x2_t v = __builtin_amdgcn_cvt_pk_bf16_f32(a, b);
    union { bf16x2_t v; unsigned u; } c; c.v = v; return c.u;
}
#else
__device__ __forceinline__ unsigned pk2bf(float a, float b) {
    union { float f; unsigned u; } x, y; x.f = a; y.f = b;
    unsigned ra = x.u + 0x7FFFu + ((x.u >> 16) & 1u);
    unsigned rb = y.u + 0x7FFFu + ((y.u >> 16) & 1u);
    return (ra >> 16) | (rb & 0xFFFF0000u);
}
#endif

// ------- fused pre-pass: K fp32->bf16 (blocks 0..3071)  |  V transpose (rest) -------
#define KCONV_BLOCKS (NBH * SQ * DH / 8 / 256)   // 3072
__global__ __launch_bounds__(256)
void prepass(const float* __restrict__ K, short* __restrict__ Kb,
             const float* __restrict__ V, short* __restrict__ Vt) {
    __shared__ float Ls[64][68];   // transpose staging (+4 pad)
    if (blockIdx.x < KCONV_BLOCKS) {
        const size_t i = (size_t)(blockIdx.x * 256 + threadIdx.x) * 8;
        f32x4 a = *(const f32x4*)&K[i];
        f32x4 b = *(const f32x4*)&K[i + 4];
        unsigned o[4] = { pk2bf(a[0], a[1]), pk2bf(a[2], a[3]),
                          pk2bf(b[0], b[1]), pk2bf(b[2], b[3]) };
        *(i32x4*)&Kb[i] = *(i32x4*)o;
        return;
    }
    const int bx = blockIdx.x - KCONV_BLOCKS;
    const int st = bx & 31;       // s tile
    const int bh = bx >> 5;
    const int b = bh / NH, h = bh % NH;
    const int s0 = st * 64;
    const float* src = V + ((size_t)b * SQ * NH + (size_t)h) * DH;
    const int dg = threadIdx.x & 15;   // d = 4*dg
    const int sl = threadIdx.x >> 4;   // 0..15
    #pragma unroll
    for (int p = 0; p < 4; ++p) {
        const int row = p * 16 + sl;
        *(f32x4*)&Ls[row][dg * 4] =
            *(const f32x4*)&src[(size_t)(s0 + row) * (NH * DH) + dg * 4];
    }
    __syncthreads();
    const int dr = threadIdx.x >> 2;        // d row 0..63
    const int sc = (threadIdx.x & 3) * 16;  // s chunk
    unsigned out[8];
    #pragma unroll
    for (int jj = 0; jj < 8; ++jj)
        out[jj] = pk2bf(Ls[sc + 2 * jj][dr], Ls[sc + 2 * jj + 1][dr]);
    short* dst = Vt + (size_t)bh * DH * SQ + (size_t)dr * SQ + s0 + sc;
    *(i32x4*)(dst)     = *(i32x4*)&out[0];
    *(i32x4*)(dst + 8) = *(i32x4*)&out[4];
}

// ---------------- main fused attention (32x32x16 MFMA, static dbuf) ----------------
__global__ __launch_bounds__(256, 3)
void attn_fused_kernel(const float* __restrict__ Q,
                       const short* __restrict__ Kb,   // bf16 [BH][S][D]
                       const short* __restrict__ Vtg,  // bf16 [BH][D][S]
                       float* __restrict__ O) {
    // Flat LDS arena, all tile offsets compile-time:
    //   buf b (b=0,1): K tile at b*16384 + {0,4096}, V tile at b*16384 + {8192,12288}
    // XOR chunk swizzle (chunk c of row r at c^(r&7)); unpadded 128B rows.
    __shared__ __align__(16) char L[32768];

    const int tid  = threadIdx.x;
    const int lane = tid & 63;
    const int w    = tid >> 6;
    const int m31  = lane & 31;     // MFMA row/col index
    const int hl   = lane >> 5;     // half-wave 0/1
    const int l7   = lane & 7;

    // ---- XCD-locality swizzle: dispatch round-robins XCDs by (bx & 7).
    // Give XCD x heads 6x..6x+5 -> per-XCD K/V working set = 6 heads x 512 KB
    // bf16 = 3.1 MB < 4 MB L2; all 96 blocks of an XCD co-resident (3/CU).
    const int bx  = blockIdx.x;
    const int xcd = bx & 7;
    const int i96 = bx >> 3;          // 0..95
    const int bh  = xcd * 6 + (i96 % 6);
    const int qt  = i96 / 6;          // 0..15
    const int q0 = qt * QTILE;

    const float* Qb  = Q   + (size_t)bh * SQ * DH;
    const short* Kbh = Kb  + (size_t)bh * SQ * DH;
    const short* Vbh = Vtg + (size_t)bh * DH * SQ;
    float*       Ob  = O   + (size_t)bh * SQ * DH;

    // scale folded into Q, exp as exp2: 1/sqrt(768) * log2(e)
    const float qscale = 0.03608439182435161f * 1.4426950408889634f;

    // ---- Q fragments (B operand: n=m31 -> q row, k=16*s+8*hl+j) ----
    short8 qf[4];
    {
        const int qrow = q0 + 32 * w + m31;
        #pragma unroll
        for (int s = 0; s < 4; ++s) {
            const float* src = Qb + (size_t)qrow * DH + 16 * s + 8 * hl;
            f32x4 qa = *(const f32x4*)src;
            f32x4 qb = *(const f32x4*)(src + 4);
            union { unsigned u[4]; short8 v; } f;
            f.u[0] = pk2bf(qa[0] * qscale, qa[1] * qscale);
            f.u[1] = pk2bf(qa[2] * qscale, qa[3] * qscale);
            f.u[2] = pk2bf(qb[0] * qscale, qb[1] * qscale);
            f.u[3] = pk2bf(qb[2] * qscale, qb[3] * qscale);
            qf[s] = f.v;
        }
    }

    // ---- staging source pointers (lane-constant swizzle), bumped per iter ----
    const int gk = (lane & 7) ^ (lane >> 3);
    const int rr = w * 8 + (lane >> 3);
    const short* kg0 = Kbh + (size_t)rr * DH + gk * 8;
    const short* kg1 = kg0 + 32 * DH;
    const short* vg0 = Vbh + (size_t)rr * SQ + gk * 8;
    const short* vg1 = vg0 + 32 * SQ;
    const int wslot = w * 1024;   // scalar

    // ---- loop-invariant per-lane LDS frag addresses (bytes) ----
    // frag row m31 (+32 via +4096 imm), global chunk (2s+hl) at LDS chunk ^(m31&7)
    int aoff[4];
    #pragma unroll
    for (int s = 0; s < 4; ++s) aoff[s] = m31 * 128 + (((2 * s + hl) ^ l7) * 16);

    f32x16 o0 = {}, o1 = {};
    float lp = 0.f;

    // issue next pending K/V tile into buffer base bb (0 or 16384), bump pointers
    auto issue = [&](int bb) {
        load_lds16(kg0, L + bb + wslot);
        load_lds16(kg1, L + bb + 4096 + wslot);
        load_lds16(vg0, L + bb + 8192 + wslot);
        load_lds16(vg1, L + bb + 12288 + wslot);
        kg0 += KTILE * DH; kg1 += KTILE * DH;
        vg0 += KTILE;      vg1 += KTILE;
    };

    // exp + in-register C->A relayout (branchless); consumes one f32x16 S half
    auto softmax_pack = [&](const f32x16& sv, short8* dst) {
        #pragma unroll
        for (int wd = 0; wd < 2; ++wd) {
            float p[8];
            #pragma unroll
            for (int j = 0; j < 8; ++j)
                p[j] = __builtin_amdgcn_exp2f(sv[8 * wd + j]);
            lp += ((p[0] + p[1]) + (p[2] + p[3])) +
                  ((p[4] + p[5]) + (p[6] + p[7]));
            unsigned a0 = pk2bf(p[0], p[1]);   // kk 4hl+{0,1}
            unsigned a1 = pk2bf(p[2], p[3]);   // kk 4hl+{2,3}
            unsigned b0 = pk2bf(p[4], p[5]);   // kk 8+4hl+{0,1}
            unsigned b1 = pk2bf(p[6], p[7]);   // kk 8+4hl+{2,3}
            unsigned r0 = (unsigned)__shfl_xor((int)(hl ? a0 : b0), 32, 64);
            unsigned r1 = (unsigned)__shfl_xor((int)(hl ? a1 : b1), 32, 64);
            union { unsigned u[4]; short8 v; } fr;
            fr.u[0] = hl ? r0 : a0;
            fr.u[1] = hl ? r1 : a1;
            fr.u[2] = hl ? b0 : r0;
            fr.u[3] = hl ? b1 : r1;
            dst[wd] = fr.v;
        }
    };

    // one K-tile step on buffer base bb (constant-folded after inlining)
    auto compute = [&](int bb) {
        f32x16 s0 = {}, s1 = {};
        #pragma unroll
        for (int s = 0; s < 4; ++s) {
            short8 ka0 = *(const short8*)(L + bb + aoff[s]);
            short8 ka1 = *(const short8*)(L + bb + 4096 + aoff[s]);
            s0 = MFMA32(ka0, qf[s], s0);
            s1 = MFMA32(ka1, qf[s], s1);
        }
        short8 pfrag[4];
        softmax_pack(s0, &pfrag[0]);
        softmax_pack(s1, &pfrag[2]);
        #pragma unroll
        for (int s = 0; s < 4; ++s) {
            short8 vb0 = *(const short8*)(L + bb + 8192 + aoff[s]);
            short8 vb1 = *(const short8*)(L + bb + 12288 + aoff[s]);
            o0 = MFMA32(pfrag[s], vb0, o0);
            o1 = MFMA32(pfrag[s], vb1, o1);
        }
    };

    issue(0);   // prologue prefetch (iter 0 -> buf0)
    for (int it = 0; it < NITER; it += 2) {
        __syncthreads();          // buf0 tiles ready; buf1 free
        issue(16384);             // iter it+1 -> buf1, flies over compute
        compute(0);
        __syncthreads();          // buf1 tiles ready; buf0 free
        if (it + 2 < NITER) issue(0);   // iter it+2 -> buf0
        compute(16384);
    }

    // ---- finalize: l(q=m31) = lp(lane) + lp(lane^32); invert; scatter ----
    float v = lp;
    v += __shfl_xor(v, 32, 64);
    const float linv = 1.0f / v;

    #pragma unroll
    for (int dt = 0; dt < 2; ++dt) {
        const f32x16& o = dt ? o1 : o0;
        #pragma unroll
        for (int reg = 0; reg < 16; ++reg) {
            const int qp = (reg & 3) + 8 * (reg >> 2) + 4 * hl;
            const float rl = __shfl(linv, qp, 64);
            const int q = q0 + 32 * w + qp;
            Ob[(size_t)q * DH + 32 * dt + m31] = o[reg] * rl;
        }
    }
}

extern "C" void kernel_launch(void* const* d_in, const int* in_sizes, int n_in,
                              void* d_out, int out_size, void* d_ws, size_t ws_size,
                              hipStream_t stream) {
    const float* Q = (const float*)d_in[0];
    const float* K = (const float*)d_in[1];
    const float* V = (const float*)d_in[2];
    float* O = (float*)d_out;

    // workspace: bf16 K (12.6 MB) + bf16 V^T (12.6 MB)
    short* Kb  = (short*)d_ws;
    short* Vtg = Kb + (size_t)NBH * SQ * DH;

    prepass<<<dim3(KCONV_BLOCKS + NBH * 32), dim3(256), 0, stream>>>(K, Kb, V, Vtg);
    // 768 blocks, XCD-swizzled (head-locality in per-XCD L2); 32 KB LDS, 3 blocks/CU
    attn_fused_kernel<<<dim3(NBH * NQT), dim3(256), 0, stream>>>(Q, Kb, Vtg, O);
}